// Round 11
// baseline (351.367 us; speedup 1.0000x reference)
//
#include <hip/hip_runtime.h>
#include <cstddef>

#define DIM 128
#define DH 64
#define NC 40
#define NBLKA 1024
#define BKT 512          // nodes per coarse bucket (dst >> 9)

typedef short bf16x8 __attribute__((ext_vector_type(8)));
typedef float f32x4  __attribute__((ext_vector_type(4)));

__device__ __forceinline__ unsigned short f2bf(float f) {
    unsigned int u = __float_as_uint(f);
    u += 0x7FFFu + ((u >> 16) & 1u);   // RNE (no NaNs here)
    return (unsigned short)(u >> 16);
}
__device__ __forceinline__ float bf2f(unsigned short h) {
    return __uint_as_float(((unsigned int)h) << 16);
}

// ==================== Pass A1: per-block bucket histogram (+ weight conv) ====================
__global__ __launch_bounds__(256) void kA1(
    const int* __restrict__ dstv, int E, int CHUNK,
    int* __restrict__ cnt /* [NBLKA][NBbkt] */, int NBbkt,
    const float* __restrict__ W1, const float* __restrict__ W2,
    unsigned short* __restrict__ W1bf, unsigned short* __restrict__ W2bf)
{
    int b = blockIdx.x;
    if (b < NBLKA) {
        __shared__ int h[256];
        for (int i = threadIdx.x; i < 256; i += 256) h[i] = 0;
        __syncthreads();
        int lo = b * CHUNK, hi = min(E, lo + CHUNK);
        for (int e0 = lo + 4 * threadIdx.x; e0 < hi; e0 += 1024) {
            if (e0 + 4 <= hi) {
                int4 d4 = *(const int4*)(dstv + e0);
                atomicAdd(&h[d4.x >> 9], 1);
                atomicAdd(&h[d4.y >> 9], 1);
                atomicAdd(&h[d4.z >> 9], 1);
                atomicAdd(&h[d4.w >> 9], 1);
            } else {
                for (int e = e0; e < hi; ++e) atomicAdd(&h[dstv[e] >> 9], 1);
            }
        }
        __syncthreads();
        for (int i = threadIdx.x; i < NBbkt; i += 256)
            cnt[(size_t)b * NBbkt + i] = h[i];
    } else {
        int i = (b - NBLKA) * 256 + threadIdx.x;
        if (i < DIM * DIM) W1bf[i] = f2bf(W1[i]);
        else if (i < DIM * DIM + DH * DIM) {
            int j = i - DIM * DIM;
            W2bf[j] = f2bf(W2[j]);
        }
    }
}

// ==================== Pass A2a: per-bucket column scan over blocks ====================
__global__ __launch_bounds__(256) void kA2a(
    int* __restrict__ cnt /* becomes exclOff */, int* __restrict__ total, int NBbkt)
{
    __shared__ int wsum[4];
    int b = blockIdx.x;      // bucket
    int t = threadIdx.x;
    int v[4]; int s = 0;
    #pragma unroll
    for (int i = 0; i < 4; ++i) { v[i] = cnt[(size_t)(4 * t + i) * NBbkt + b]; s += v[i]; }
    int lane = t & 63, wv = t >> 6;
    int si = s;
    #pragma unroll
    for (int off = 1; off < 64; off <<= 1) {
        int x = __shfl_up(si, off);
        if (lane >= off) si += x;
    }
    if (lane == 63) wsum[wv] = si;
    __syncthreads();
    int wbase = 0;
    for (int i = 0; i < wv; ++i) wbase += wsum[i];
    int run = wbase + si - s;
    #pragma unroll
    for (int i = 0; i < 4; ++i) { cnt[(size_t)(4 * t + i) * NBbkt + b] = run; run += v[i]; }
    if (t == 255) total[b] = run;
}

// ==================== Pass A2b: bucket base scan ====================
__global__ __launch_bounds__(256) void kA2b(
    const int* __restrict__ total, int* __restrict__ bucketBase, int NBbkt)
{
    __shared__ int wsum[4];
    int t = threadIdx.x;
    int v = (t < NBbkt) ? total[t] : 0;
    int lane = t & 63, wv = t >> 6;
    int si = v;
    #pragma unroll
    for (int off = 1; off < 64; off <<= 1) {
        int x = __shfl_up(si, off);
        if (lane >= off) si += x;
    }
    if (lane == 63) wsum[wv] = si;
    __syncthreads();
    int wbase = 0;
    for (int i = 0; i < wv; ++i) wbase += wsum[i];
    int incl = wbase + si;
    if (t < NBbkt) bucketBase[t + 1] = incl;
    if (t == 0) bucketBase[0] = 0;
}

// ==================== Pass A3: partition into buckets (+ feat conv) ====================
// staging record: {csrword = (w15<<17)|src17, dstLocal}
__global__ __launch_bounds__(256) void kA3(
    const int* __restrict__ srcv, const int* __restrict__ dstv,
    const float* __restrict__ wv_, int E, int CHUNK,
    const int* __restrict__ exclOff, const int* __restrict__ bucketBase,
    uint2* __restrict__ staging, int NBbkt,
    const float4* __restrict__ feat4, ushort4* __restrict__ featbf4, int n8)
{
    int b = blockIdx.x;
    if (b < NBLKA) {
        __shared__ int cur[256];
        for (int i = threadIdx.x; i < NBbkt; i += 256)
            cur[i] = bucketBase[i] + exclOff[(size_t)b * NBbkt + i];
        __syncthreads();
        int lo = b * CHUNK, hi = min(E, lo + CHUNK);
        for (int e0 = lo + 4 * threadIdx.x; e0 < hi; e0 += 1024) {
            if (e0 + 4 <= hi) {
                int4   d4 = *(const int4*)(dstv + e0);
                int4   s4 = *(const int4*)(srcv + e0);
                float4 w4 = *(const float4*)(wv_ + e0);
                int dd[4] = {d4.x, d4.y, d4.z, d4.w};
                int ss[4] = {s4.x, s4.y, s4.z, s4.w};
                float ww[4] = {w4.x, w4.y, w4.z, w4.w};
                #pragma unroll
                for (int i = 0; i < 4; ++i) {
                    unsigned q = (unsigned)(ww[i] * 32767.f + 0.5f);
                    unsigned word = (q << 17) | (unsigned)ss[i];
                    int pos = atomicAdd(&cur[dd[i] >> 9], 1);
                    staging[pos] = make_uint2(word, (unsigned)(dd[i] & (BKT - 1)));
                }
            } else {
                for (int e = e0; e < hi; ++e) {
                    int d = dstv[e];
                    unsigned q = (unsigned)(wv_[e] * 32767.f + 0.5f);
                    unsigned word = (q << 17) | (unsigned)srcv[e];
                    int pos = atomicAdd(&cur[d >> 9], 1);
                    staging[pos] = make_uint2(word, (unsigned)(d & (BKT - 1)));
                }
            }
        }
    } else {
        int i = (b - NBLKA) * 256 + threadIdx.x;   // 8-float chunk
        if (i < n8) {
            float4 x = feat4[2 * i], y = feat4[2 * i + 1];
            ushort4 o1, o2;
            o1.x = f2bf(x.x); o1.y = f2bf(x.y); o1.z = f2bf(x.z); o1.w = f2bf(x.w);
            o2.x = f2bf(y.x); o2.y = f2bf(y.y); o2.z = f2bf(y.z); o2.w = f2bf(y.w);
            featbf4[2 * i] = o1; featbf4[2 * i + 1] = o2;
        }
    }
}

// ==================== Pass B: per-bucket local CSR build ====================
__global__ __launch_bounds__(256) void kB(
    const uint2* __restrict__ staging, const int* __restrict__ bucketBase,
    unsigned* __restrict__ csr, int* __restrict__ row_start, int n)
{
    __shared__ int bins[BKT];
    __shared__ int cur[BKT];
    __shared__ int wsum[4];
    int b = blockIdx.x;
    int base = bucketBase[b], cntE = bucketBase[b + 1] - base;
    int t = threadIdx.x;
    for (int i = t; i < BKT; i += 256) bins[i] = 0;
    __syncthreads();
    for (int i = t; i < cntE; i += 256)
        atomicAdd(&bins[staging[base + i].y], 1);
    __syncthreads();
    int b0 = bins[2 * t], b1 = bins[2 * t + 1];
    int s = b0 + b1;
    int lane = t & 63, wv = t >> 6;
    int si = s;
    #pragma unroll
    for (int off = 1; off < 64; off <<= 1) {
        int x = __shfl_up(si, off);
        if (lane >= off) si += x;
    }
    if (lane == 63) wsum[wv] = si;
    __syncthreads();
    int wbase = 0;
    for (int i = 0; i < wv; ++i) wbase += wsum[i];
    int excl = wbase + si - s;
    int v0 = b * BKT + 2 * t;
    if (v0 <= n)     row_start[v0]     = base + excl;
    if (v0 + 1 <= n) row_start[v0 + 1] = base + excl + b0;
    cur[2 * t]     = base + excl;
    cur[2 * t + 1] = base + excl + b0;
    __syncthreads();
    for (int i = t; i < cntE; i += 256) {
        uint2 r = staging[base + i];
        int pos = atomicAdd(&cur[r.y], 1);
        csr[pos] = r.x;
    }
}

// ==================== gather 1: agg = D^-1 A feat (bf16, pre-swizzled out) ====================
__global__ __launch_bounds__(256) void k_gather1(
    const unsigned short* __restrict__ feat, const int* __restrict__ row_start,
    const unsigned* __restrict__ csr, float* __restrict__ deg,
    unsigned short* __restrict__ aggbf, int n)
{
    constexpr int G = 16, EPW = 4;
    int lane = threadIdx.x & 63;
    int q    = lane & (G - 1);
    int sub  = lane / G;
    int wid  = (int)((blockIdx.x * blockDim.x + threadIdx.x) >> 6);
    int nw   = (int)((gridDim.x * blockDim.x) >> 6);
    for (int v = wid; v < n; v += nw) {
        int beg = row_start[v], end = row_start[v + 1];
        float acc[8];
        #pragma unroll
        for (int e = 0; e < 8; ++e) acc[e] = 0.f;
        float dsum = 0.f;
        for (int b = beg; b < end; b += 64) {
            int cnt = end - b; if (cnt > 64) cnt = 64;
            unsigned word = (lane < cnt) ? csr[b + lane] : 0u;
            dsum += (float)(word >> 17) * (1.f / 32767.f);
            int iters = (cnt + EPW - 1) / EPW;
            for (int j = 0; j < iters; ++j) {
                unsigned wj = (unsigned)__shfl((int)word, j * EPW + sub);
                int   s   = (int)(wj & 0x1FFFFu);
                float wgt = (float)(wj >> 17) * (1.f / 32767.f);
                bf16x8 f = *(const bf16x8*)(feat + (size_t)s * DIM + q * 8);
                #pragma unroll
                for (int e = 0; e < 8; ++e)
                    acc[e] += wgt * bf2f((unsigned short)f[e]);
            }
        }
        #pragma unroll
        for (int m = 32; m >= G; m >>= 1)
            #pragma unroll
            for (int e = 0; e < 8; ++e) acc[e] += __shfl_xor(acc[e], m);
        #pragma unroll
        for (int m = 32; m >= 1; m >>= 1) dsum += __shfl_xor(dsum, m);
        if (lane == 0) deg[v] = dsum;
        float dg = dsum > 1.f ? dsum : 1.f;
        float inv = 1.f / dg;
        if (lane < G) {
            bf16x8 o;
            #pragma unroll
            for (int e = 0; e < 8; ++e) o[e] = (short)f2bf(acc[e] * inv);
            int p = q ^ (v & 7);   // pre-swizzle for dense1z LDS layout
            *(bf16x8*)(aggbf + (size_t)v * DIM + p * 8) = o;
        }
    }
}

// ==================== gather 2 + logits: emb = D^-1 A Z + b2; logits = emb@W3^T+b3 ====================
#define SW3P 66
__global__ __launch_bounds__(256) void k_gather2(
    const unsigned short* __restrict__ Zbf, const int* __restrict__ row_start,
    const unsigned* __restrict__ csr, const float* __restrict__ deg,
    const float* __restrict__ b2, const float* __restrict__ W3,
    const float* __restrict__ b3,
    float* __restrict__ out_emb, float* __restrict__ out_log, int n)
{
    __shared__ float sW3[NC * SW3P];
    __shared__ float sb3[NC];
    constexpr int G = 8, EPW = 8;
    int t = threadIdx.x;
    for (int i = t; i < NC * DH; i += 256) {
        int cc = i >> 6, k = i & 63;
        sW3[cc * SW3P + k] = W3[i];
    }
    if (t < NC) sb3[t] = b3[t];
    __syncthreads();

    int lane = t & 63;
    int q    = lane & (G - 1);
    int sub  = lane >> 3;           // 0..7
    int wid  = (int)((blockIdx.x * blockDim.x + t) >> 6);
    int nw   = (int)((gridDim.x * blockDim.x) >> 6);
    for (int v = wid; v < n; v += nw) {
        int beg = row_start[v], end = row_start[v + 1];
        float acc[8];
        #pragma unroll
        for (int e = 0; e < 8; ++e) acc[e] = 0.f;
        for (int b = beg; b < end; b += 64) {
            int cnt = end - b; if (cnt > 64) cnt = 64;
            unsigned word = (lane < cnt) ? csr[b + lane] : 0u;
            int iters = (cnt + EPW - 1) / EPW;
            for (int j = 0; j < iters; ++j) {
                unsigned wj = (unsigned)__shfl((int)word, j * EPW + sub);
                int   s   = (int)(wj & 0x1FFFFu);
                float wgt = (float)(wj >> 17) * (1.f / 32767.f);
                bf16x8 f = *(const bf16x8*)(Zbf + (size_t)s * DH + q * 8);
                #pragma unroll
                for (int e = 0; e < 8; ++e)
                    acc[e] += wgt * bf2f((unsigned short)f[e]);
            }
        }
        #pragma unroll
        for (int m = 32; m >= G; m >>= 1)
            #pragma unroll
            for (int e = 0; e < 8; ++e) acc[e] += __shfl_xor(acc[e], m);

        // emb slice (all lanes hold it for their q-group)
        float dg = deg[v]; dg = dg > 1.f ? dg : 1.f;
        float inv = 1.f / dg;
        float emb[8];
        #pragma unroll
        for (int e = 0; e < 8; ++e) emb[e] = acc[e] * inv + b2[q * 8 + e];

        if (lane < G) {
            float4* dst = (float4*)(out_emb + (size_t)v * DH + q * 8);
            dst[0] = make_float4(emb[0], emb[1], emb[2], emb[3]);
            dst[1] = make_float4(emb[4], emb[5], emb[6], emb[7]);
        }

        // logits: lane (sub,q) computes partials for classes c = sub*5+j over k=8q..8q+7
        float part[5];
        #pragma unroll
        for (int j = 0; j < 5; ++j) {
            int c = sub * 5 + j;
            const float* wrow = &sW3[c * SW3P + q * 8];
            float p = 0.f;
            #pragma unroll
            for (int e = 0; e < 8; ++e) p += emb[e] * wrow[e];
            part[j] = p;
        }
        #pragma unroll
        for (int m = 1; m <= 4; m <<= 1)
            #pragma unroll
            for (int j = 0; j < 5; ++j) part[j] += __shfl_xor(part[j], m);
        if (q == 0) {
            #pragma unroll
            for (int j = 0; j < 5; ++j) {
                int c = sub * 5 + j;
                out_log[(size_t)v * NC + c] = part[j] + sb3[c];
            }
        }
    }
}

// ==================== persistent fused MFMA dense: Z = relu(agg@W1^T+b1) @ W2^T ====================
__global__ __launch_bounds__(256) void k_dense1z(
    const unsigned short* __restrict__ aggbf,
    const unsigned short* __restrict__ W1bf, const float* __restrict__ b1,
    const unsigned short* __restrict__ W2bf,
    unsigned short* __restrict__ Zbf, int n, int ntiles)
{
    __shared__ unsigned short sAgg[64 * 128];
    __shared__ unsigned short sW1[128 * 128];
    __shared__ unsigned short sW2[64 * 128];
    __shared__ unsigned short sHid[64 * 128];
    int t = threadIdx.x;
    int lane = t & 63;
    int w = t >> 6;

    // weights staged ONCE per persistent block (first in-loop barrier covers this)
    #pragma unroll
    for (int i = 0; i < 8; ++i) {
        int B = t + 256 * i;
        int r = B >> 4, q = B & 15;
        bf16x8 v = *(const bf16x8*)(W1bf + r * 128 + q * 8);
        *(bf16x8*)&sW1[r * 128 + ((q ^ (r & 7)) * 8)] = v;
    }
    #pragma unroll
    for (int i = 0; i < 4; ++i) {
        int B = t + 256 * i;
        int r = B >> 4, q = B & 15;
        bf16x8 v = *(const bf16x8*)(W2bf + r * 128 + q * 8);
        *(bf16x8*)&sW2[r * 128 + ((q ^ (r & 7)) * 8)] = v;
    }

    int c = lane & 15;
    int g = lane >> 4;
    int ar = 16 * w + c;
    float b1v[8];
    #pragma unroll
    for (int nt = 0; nt < 8; ++nt) b1v[nt] = b1[nt * 16 + c];

    for (int tile = blockIdx.x; tile < ntiles; tile += gridDim.x) {
        int row0 = tile * 64;
        #pragma unroll
        for (int i = 0; i < 4; ++i) {
            int B = t + 256 * i;
            int r = B >> 4, p = B & 15;
            *(bf16x8*)&sAgg[r * 128 + p * 8] =
                *(const bf16x8*)(aggbf + (size_t)(row0 + r) * DIM + p * 8);
        }
        __syncthreads();

        bf16x8 a1[4];
        #pragma unroll
        for (int ks = 0; ks < 4; ++ks) {
            int q = ks * 4 + g;
            a1[ks] = *(const bf16x8*)&sAgg[ar * 128 + ((q ^ (ar & 7)) * 8)];
        }
        f32x4 acc[8];
        #pragma unroll
        for (int nt = 0; nt < 8; ++nt)
            acc[nt] = (f32x4){b1v[nt], b1v[nt], b1v[nt], b1v[nt]};
        #pragma unroll
        for (int ks = 0; ks < 4; ++ks) {
            #pragma unroll
            for (int nt = 0; nt < 8; ++nt) {
                int rn = nt * 16 + c;
                int q = ks * 4 + g;
                bf16x8 b = *(const bf16x8*)&sW1[rn * 128 + ((q ^ (rn & 7)) * 8)];
                acc[nt] = __builtin_amdgcn_mfma_f32_16x16x32_bf16(a1[ks], b, acc[nt], 0, 0, 0);
            }
        }
        #pragma unroll
        for (int nt = 0; nt < 8; ++nt) {
            #pragma unroll
            for (int rg = 0; rg < 4; ++rg) {
                float v = acc[nt][rg];
                v = v > 0.f ? v : 0.f;
                int hr = 16 * w + 4 * g + rg;
                int col = nt * 16 + c;
                int qq = col >> 3, oo = col & 7;
                sHid[hr * 128 + ((qq ^ (hr & 7)) * 8) + oo] = f2bf(v);
            }
        }
        __syncthreads();

        bf16x8 a2[4];
        #pragma unroll
        for (int ks = 0; ks < 4; ++ks) {
            int q = ks * 4 + g;
            a2[ks] = *(const bf16x8*)&sHid[ar * 128 + ((q ^ (ar & 7)) * 8)];
        }
        f32x4 acc2[4];
        #pragma unroll
        for (int nt = 0; nt < 4; ++nt) acc2[nt] = (f32x4){0.f, 0.f, 0.f, 0.f};
        #pragma unroll
        for (int ks = 0; ks < 4; ++ks) {
            #pragma unroll
            for (int nt = 0; nt < 4; ++nt) {
                int rn = nt * 16 + c;
                int q = ks * 4 + g;
                bf16x8 b = *(const bf16x8*)&sW2[rn * 128 + ((q ^ (rn & 7)) * 8)];
                acc2[nt] = __builtin_amdgcn_mfma_f32_16x16x32_bf16(a2[ks], b, acc2[nt], 0, 0, 0);
            }
        }
        #pragma unroll
        for (int nt = 0; nt < 4; ++nt) {
            #pragma unroll
            for (int rg = 0; rg < 4; ++rg) {
                int m = row0 + 16 * w + 4 * g + rg;
                if (m < n) Zbf[(size_t)m * DH + nt * 16 + c] = f2bf(acc2[nt][rg]);
            }
        }
        __syncthreads();   // guard sHid/sAgg reuse across tiles
    }
}

// ==================== launch ====================
extern "C" void kernel_launch(void* const* d_in, const int* in_sizes, int n_in,
                              void* d_out, int out_size, void* d_ws, size_t ws_size,
                              hipStream_t stream)
{
    const float* feat = (const float*)d_in[0];
    const int*   eidx = (const int*)d_in[1];
    const float* ew   = (const float*)d_in[2];
    const float* W1   = (const float*)d_in[3];
    const float* b1   = (const float*)d_in[4];
    const float* W2   = (const float*)d_in[5];
    const float* b2   = (const float*)d_in[6];
    const float* W3   = (const float*)d_in[7];
    const float* b3   = (const float*)d_in[8];

    int E = in_sizes[2];
    int n = in_sizes[0] / DIM;
    int npad = (n + 63) & ~63;
    int NBbkt = (n + BKT - 1) / BKT;     // 196 for n=100000 (<=256 required)
    int CHUNK = (((E + NBLKA - 1) / NBLKA) + 3) & ~3;

    const int* srcv = eidx;
    const int* dstv = eidx + E;

    float* out_emb = (float*)d_out;
    float* out_log = out_emb + (size_t)n * DH;

    size_t nf = (size_t)n * DIM;

    char* wsb = (char*)d_ws;
    size_t off = 0;
    auto alloc = [&](size_t bytes) -> void* {
        void* p = wsb + off;
        off = (off + bytes + 255) & ~(size_t)255;
        return p;
    };
    unsigned short* aggbf   = (unsigned short*)alloc((size_t)npad * DIM * 2);
    unsigned short* Zbf     = (unsigned short*)alloc((size_t)npad * DH * 2);
    unsigned short* featbf  = (unsigned short*)alloc(nf * 2);
    unsigned short* W1bf    = (unsigned short*)alloc((size_t)DIM * DIM * 2);
    unsigned short* W2bf    = (unsigned short*)alloc((size_t)DH * DIM * 2);
    float*          deg     = (float*)alloc((size_t)n * 4);
    int*            row_start = (int*)alloc((size_t)(n + 1) * 4);
    unsigned*       csr     = (unsigned*)alloc((size_t)E * 4);
    uint2*          staging = (uint2*)alloc((size_t)E * 8);
    int*            cnt     = (int*)alloc((size_t)NBLKA * NBbkt * 4);
    int*            total   = (int*)alloc((size_t)NBbkt * 4);
    int*            bucketBase = (int*)alloc((size_t)(NBbkt + 1) * 4);

    // A1: bucket histogram per block (+ weight conversion piggyback)
    int WB = (DIM * DIM + DH * DIM + 255) / 256;
    kA1<<<NBLKA + WB, 256, 0, stream>>>(dstv, E, CHUNK, cnt, NBbkt, W1, W2, W1bf, W2bf);
    // A2: offsets
    kA2a<<<NBbkt, 256, 0, stream>>>(cnt, total, NBbkt);
    kA2b<<<1, 256, 0, stream>>>(total, bucketBase, NBbkt);
    // A3: partition (+ feature bf16 conversion piggyback)
    int n8 = (int)(nf / 8);
    int FB = (n8 + 255) / 256;
    kA3<<<NBLKA + FB, 256, 0, stream>>>(srcv, dstv, ew, E, CHUNK, cnt, bucketBase,
                                        staging, NBbkt, (const float4*)feat,
                                        (ushort4*)featbf, n8);
    // B: local CSR build
    kB<<<NBbkt, 256, 0, stream>>>(staging, bucketBase, csr, row_start, n);

    // aggregate -> fused dense (persistent) -> aggregate+logits
    int gblk = (n + 3) / 4;
    k_gather1<<<gblk, 256, 0, stream>>>(featbf, row_start, csr, deg, aggbf, n);
    int ntiles = npad / 64;
    int pgrid = ntiles < 512 ? ntiles : 512;
    k_dense1z<<<pgrid, 256, 0, stream>>>(aggbf, W1bf, b1, W2bf, Zbf, n, ntiles);
    k_gather2<<<gblk, 256, 0, stream>>>(Zbf, row_start, csr, deg, b2, W3, b3,
                                        out_emb, out_log, n);
}